// Round 3
// baseline (37.696 us; speedup 1.0000x reference)
//
#include <hip/hip_runtime.h>
#include <math.h>

// Problem constants (from reference setup_inputs):
//   x:  (256, 197, 384) f32   — row 0 is CLS, rows 1..196 are "nodes"
//   ea: (256, 196, 384) f32
//   out:(256, 50, 384)  f32   — [CLS, 49 selected nodes in ascending-score order]
#define NB      256
#define NNODES  196
#define NC      384
#define SEQ     197
#define START   147          // 196//4*3
#define KEEP    49           // 196 - 147
#define OUTROWS 50

#define NT      960          // 15 waves
#define NWAVE   15
#define RG      10           // row-groups in phase 1
#define C4      96           // NC/4 float4 columns
#define P1IT    20           // fixed trip count: rows rg + 10*it, it<20 (196..199 predicated off)
#define NPW     14           // nodes per wave strip (15*14 = 210 >= 196)

__global__ __launch_bounds__(NT)
void pooling_block_kernel(const float* __restrict__ x,
                          const float* __restrict__ ea,
                          float* __restrict__ out) {
    __shared__ double partial[RG][NC];            // 30 KB
    __shared__ alignas(16) float imp[NC];
    __shared__ float scores[NNODES];
    __shared__ int   sel[KEEP];

    const int b   = blockIdx.x;
    const int tid = threadIdx.x;                  // 0..959

    // ---- Phase 1: per-channel mean over 196 rows ----
    // Fixed 20-iteration unroll; all 20 float4 loads issued before the
    // accumulation chain (max MLP). Rows 196..199 are clamped to a valid
    // address and zeroed by a predicate multiply.
    {
        const int rg = tid / C4;                  // 0..9
        const int c4 = tid % C4;
        const float4* p = (const float4*)(ea + (size_t)b * NNODES * NC) + c4;
        float4 v[P1IT];
        #pragma unroll
        for (int it = 0; it < P1IT; ++it) {
            int row = rg + RG * it;
            int r   = row < NNODES ? row : NNODES - 1;   // clamp (in-bounds)
            v[it] = p[(size_t)r * C4];
        }
        double ax = 0.0, ay = 0.0, az = 0.0, aw = 0.0;
        #pragma unroll
        for (int it = 0; it < P1IT; ++it) {
            int row = rg + RG * it;
            float pred = row < NNODES ? 1.0f : 0.0f;     // kill clamped rows
            ax += (double)(pred * v[it].x);
            ay += (double)(pred * v[it].y);
            az += (double)(pred * v[it].z);
            aw += (double)(pred * v[it].w);
        }
        partial[rg][4 * c4 + 0] = ax;
        partial[rg][4 * c4 + 1] = ay;
        partial[rg][4 * c4 + 2] = az;
        partial[rg][4 * c4 + 3] = aw;
    }
    __syncthreads();
    if (tid < NC) {
        double s = 0.0;
        #pragma unroll
        for (int rg = 0; rg < RG; ++rg) s += partial[rg][tid];
        float m = (float)(s * (1.0 / (double)NNODES));
        imp[tid] = 1.0f / (1.0f + expf(-m));
    }
    __syncthreads();

    // ---- Phase 2: node scores = dot(node_row, imp). Wave-per-node-strip. ----
    // Same accumulation expressions / butterfly order as the passing kernel
    // (bit-identical scores); loads batched 7 nodes (21 float2) at a time.
    {
        const int wave = tid >> 6;                // 0..14
        const int lane = tid & 63;
        const int wbase = wave * NPW;             // contiguous 14-node strip
        const float* nodes = x + ((size_t)b * SEQ + 1) * NC;
        const float2* imp2 = (const float2*)imp;

        float2 w[3];
        #pragma unroll
        for (int j = 0; j < 3; ++j) w[j] = imp2[lane + 64 * j];

        #pragma unroll
        for (int c = 0; c < 2; ++c) {
            float2 vv[7][3];
            #pragma unroll
            for (int i = 0; i < 7; ++i) {
                int n  = wbase + c * 7 + i;
                int nn = n < NNODES ? n : NNODES - 1;
                const float2* row2 = (const float2*)(nodes + (size_t)nn * NC);
                #pragma unroll
                for (int j = 0; j < 3; ++j) vv[i][j] = row2[lane + 64 * j];
            }
            #pragma unroll
            for (int i = 0; i < 7; ++i) {
                double acc = 0.0;
                #pragma unroll
                for (int j = 0; j < 3; ++j)
                    acc += (double)vv[i][j].x * (double)w[j].x
                         + (double)vv[i][j].y * (double)w[j].y;
                #pragma unroll
                for (int off = 32; off > 0; off >>= 1)
                    acc += __shfl_xor(acc, off);
                int n = wbase + c * 7 + i;
                if (lane == 0 && n < NNODES) scores[n] = (float)acc;
            }
        }
    }
    __syncthreads();

    // ---- Phase 3: stable ascending rank; keep ranks >= START ----
    if (tid < NNODES) {
        const float s = scores[tid];
        int rank = 0;
        for (int m = 0; m < NNODES; ++m) {
            const float sm = scores[m];
            rank += (sm < s) || (sm == s && m < tid);   // stable tie-break
        }
        if (rank >= START) sel[rank - START] = tid;
    }
    __syncthreads();

    // ---- Phase 4: write output rows (float4, coalesced) ----
    {
        const int jg = tid / C4;                  // 0..9 (row group)
        const int c4 = tid % C4;
        const float* nodes = x + ((size_t)b * SEQ + 1) * NC;
        const float4* nodes4 = (const float4*)nodes;
        const float4* cls4   = (const float4*)(x + (size_t)b * SEQ * NC);
        float4* out4         = (float4*)(out + (size_t)b * OUTROWS * NC);
        #pragma unroll
        for (int it = 0; it < 5; ++it) {
            int j = jg + RG * it;                 // 0..49
            const float4* src = (j == 0) ? cls4 : (nodes4 + (size_t)sel[j - 1] * C4);
            out4[(size_t)j * C4 + c4] = src[c4];
        }
    }
}

extern "C" void kernel_launch(void* const* d_in, const int* in_sizes, int n_in,
                              void* d_out, int out_size, void* d_ws, size_t ws_size,
                              hipStream_t stream) {
    const float* x   = (const float*)d_in[0];
    const float* ea  = (const float*)d_in[1];
    float* out       = (float*)d_out;

    hipLaunchKernelGGL(pooling_block_kernel,
                       dim3(NB), dim3(NT), 0, stream,
                       x, ea, out);
}